// Round 1
// baseline (142.040 us; speedup 1.0000x reference)
//
#include <hip/hip_runtime.h>

namespace {
constexpr int IMG_H = 376;
constexpr int IMG_W = 1248;
constexpr int CV = 16;
constexpr int CR = 32;
constexpr int CO = CV + CR;   // 48
constexpr int K3 = 27;
constexpr int BLOCK = 256;    // threads per block == rows per block
constexpr int LDS_STRIDE = CO + 1;  // 49 -> bank = (17*t + c) % 32, conflict-free
}

// Per-batch precompute: Md = rect[s] @ Trv2c[s]; copy P2[s], prd[s].
// Layout per b (32 floats): [0:16) Md, [16:28) P2, [28] prd_u, [29] prd_v
__global__ void prep_kernel(const float* __restrict__ P2,
                            const float* __restrict__ Trv2c,
                            const float* __restrict__ rect,
                            const float* __restrict__ prd,
                            const int* __restrict__ dummy,
                            float* __restrict__ mats, int B) {
    int b = threadIdx.x;
    if (b >= B) return;
    int s = dummy[b];
    float* o = mats + b * 32;
    const float* R = rect + s * 16;
    const float* T = Trv2c + s * 16;
    for (int i = 0; i < 4; ++i) {
        for (int j = 0; j < 4; ++j) {
            float acc = R[i * 4 + 0] * T[0 * 4 + j];
            acc += R[i * 4 + 1] * T[1 * 4 + j];
            acc += R[i * 4 + 2] * T[2 * 4 + j];
            acc += R[i * 4 + 3] * T[3 * 4 + j];
            o[i * 4 + j] = acc;
        }
    }
    for (int i = 0; i < 12; ++i) o[16 + i] = P2[s * 12 + i];
    o[28] = prd[s * 2 + 0];
    o[29] = prd[s * 2 + 1];
}

__global__ __launch_bounds__(BLOCK) void fuse_kernel(
        const float* __restrict__ vfeat,
        const float* __restrict__ rgb,
        const float* __restrict__ mats,
        const int* __restrict__ vcoords,
        float* __restrict__ out,
        int N) {
    const int M = N * K3;
    __shared__ float lds[BLOCK][LDS_STRIDE];

    const int t = threadIdx.x;
    const int m = blockIdx.x * BLOCK + t;

    if (m < M) {
        int n = m / K3;
        int kk = m - n * K3;
        int4 vc = ((const int4*)vcoords)[n];
        int b = vc.x;
        int dz = kk / 9;
        int rem = kk - dz * 9;
        int dy = rem / 3;
        int dx = rem - dy * 3;

        float fz = ((float)(vc.y + dz - 1) + 0.5f) * 0.1f - 3.0f;
        float fy = ((float)(vc.z + dy - 1) + 0.5f) * 0.05f - 40.0f;
        float fx = ((float)(vc.w + dx - 1) + 0.5f) * 0.05f;

        const float* Mb = mats + b * 32;
        float cam0 = Mb[0]  * fx + Mb[1]  * fy + Mb[2]  * fz + Mb[3];
        float cam1 = Mb[4]  * fx + Mb[5]  * fy + Mb[6]  * fz + Mb[7];
        float cam2 = Mb[8]  * fx + Mb[9]  * fy + Mb[10] * fz + Mb[11];
        float cam3 = Mb[12] * fx + Mb[13] * fy + Mb[14] * fz + Mb[15];

        float img0 = Mb[16] * cam0 + Mb[17] * cam1 + Mb[18] * cam2 + Mb[19] * cam3;
        float img1 = Mb[20] * cam0 + Mb[21] * cam1 + Mb[22] * cam2 + Mb[23] * cam3;
        float img2 = Mb[24] * cam0 + Mb[25] * cam1 + Mb[26] * cam2 + Mb[27] * cam3;

        float depth = img2;
        float d = fmaxf(depth, 0.001f);
        float u = img0 / d + Mb[28];
        float v = img1 / d + Mb[29];

        bool valid = (depth > 0.001f) && (u >= 0.0f) && (u <= (float)(IMG_W - 1))
                     && (v >= 0.0f) && (v <= (float)(IMG_H - 1));

        // voxel features -> LDS cols [0,16)
        const float* vp = vfeat + (size_t)n * CV;
        #pragma unroll
        for (int c = 0; c < CV; ++c) lds[t][c] = vp[c];

        if (valid) {
            float uc = fminf(fmaxf(u, 0.0f), (float)(IMG_W - 1));
            float vcl = fminf(fmaxf(v, 0.0f), (float)(IMG_H - 1));
            int x0 = (int)floorf(uc);
            int y0 = (int)floorf(vcl);
            int x1 = min(x0 + 1, IMG_W - 1);
            int y1 = min(y0 + 1, IMG_H - 1);
            float wx = uc - (float)x0;
            float wy = vcl - (float)y0;
            float w00 = (1.0f - wx) * (1.0f - wy);
            float w10 = wx * (1.0f - wy);
            float w01 = (1.0f - wx) * wy;
            float w11 = wx * wy;
            const float* base = rgb + (size_t)b * CR * IMG_H * IMG_W;
            int o00 = y0 * IMG_W + x0;
            int o10 = y0 * IMG_W + x1;
            int o01 = y1 * IMG_W + x0;
            int o11 = y1 * IMG_W + x1;
            #pragma unroll
            for (int c = 0; c < CR; ++c) {
                const float* p = base + (size_t)c * (IMG_H * IMG_W);
                float s = p[o00] * w00 + p[o10] * w10 + p[o01] * w01 + p[o11] * w11;
                lds[t][CV + c] = s;
            }
        } else {
            #pragma unroll
            for (int c = 0; c < CR; ++c) lds[t][CV + c] = 0.0f;
        }
    }

    __syncthreads();

    // coalesced write phase: this block covers rows [blockIdx*BLOCK, ...) -> 12288 floats
    size_t blockBase = (size_t)blockIdx.x * BLOCK * CO;
    size_t total = (size_t)M * CO;
    #pragma unroll 4
    for (int i = 0; i < CO; ++i) {
        int f = i * BLOCK + t;          // 0 .. BLOCK*CO-1
        int r = f / CO;
        int c = f - r * CO;
        size_t g = blockBase + (size_t)f;
        if (g < total) out[g] = lds[r][c];
    }
}

extern "C" void kernel_launch(void* const* d_in, const int* in_sizes, int n_in,
                              void* d_out, int out_size, void* d_ws, size_t ws_size,
                              hipStream_t stream) {
    const float* vfeat  = (const float*)d_in[0];
    const float* rgb    = (const float*)d_in[1];
    const float* P2     = (const float*)d_in[2];
    const float* Trv2c  = (const float*)d_in[3];
    const float* rect   = (const float*)d_in[4];
    const float* prd    = (const float*)d_in[5];
    const int* vcoords  = (const int*)d_in[6];
    const int* dummy    = (const int*)d_in[7];
    float* out = (float*)d_out;

    int B = in_sizes[7];
    int N = in_sizes[6] / 4;
    float* mats = (float*)d_ws;   // B * 32 floats

    prep_kernel<<<1, 64, 0, stream>>>(P2, Trv2c, rect, prd, dummy, mats, B);

    int M = N * K3;
    int blocks = (M + BLOCK - 1) / BLOCK;
    fuse_kernel<<<blocks, BLOCK, 0, stream>>>(vfeat, rgb, mats, vcoords, out, N);
}